// Round 6
// baseline (21.077 us; speedup 1.0000x reference)
//
#include <hip/hip_runtime.h>

// out[n,co] = (1/1225) * sum_ci Sx[n,ci] * Sw[co,ci] + bias[co]   (exact; absmax 0.0 since R2)
//   Sx[n,ci]   = sum over 32x32 spatial of x[n,ci]
//   swt[ci,co] = tapsum(w[co,ci,:,:])   (stored transposed for coalesced gemm reads)

#define XBLOCKS 1024   // 16 rows per block (4 rows per wave)

// ---- Node 1: blocks [0,1024) reduce x; blocks [1024,1280) reduce w. ----
__global__ __launch_bounds__(256) void k_reduce(const float* __restrict__ x,
                                                const float* __restrict__ w,
                                                float* __restrict__ sx,
                                                float* __restrict__ swt) {
    const int b    = blockIdx.x;
    const int tid  = threadIdx.x;
    const int lane = tid & 63;
    const int wv   = tid >> 6;
    if (b < XBLOCKS) {
        // Wave wv owns rows row0..row0+3; each row = 1024 floats = 256 float4,
        // lane reads 4 float4 per row -> 16 independent loads in flight.
        const int row0 = b * 16 + wv * 4;
        const float4* p = reinterpret_cast<const float4*>(x + (size_t)row0 * 1024);
        float s[4];
        #pragma unroll
        for (int r = 0; r < 4; ++r) {
            const float4 a = p[r * 256 + lane];
            const float4 c = p[r * 256 + 64 + lane];
            const float4 d = p[r * 256 + 128 + lane];
            const float4 e = p[r * 256 + 192 + lane];
            s[r] = ((a.x + a.y) + (a.z + a.w)) + ((c.x + c.y) + (c.z + c.w)) +
                   ((d.x + d.y) + (d.z + d.w)) + ((e.x + e.y) + (e.z + e.w));
        }
        #pragma unroll
        for (int o = 32; o >= 1; o >>= 1) {
            #pragma unroll
            for (int r = 0; r < 4; ++r) s[r] += __shfl_xor(s[r], o, 64);
        }
        if (lane < 4) sx[row0 + lane] = s[lane];  // lanes 0..3 hold full sums (shfl_xor: all lanes)
    } else {
        const int d0 = b - XBLOCKS;             // weight dim0 (= co)
        const int d1 = tid;                     // weight dim1 (= ci)
        const float4* p = reinterpret_cast<const float4*>(w + ((size_t)d0 * 256 + d1) * 16);
        float s = 0.f;
        #pragma unroll
        for (int k = 0; k < 4; ++k) {
            const float4 v = p[k];
            s += v.x + v.y + v.z + v.w;
        }
        swt[(size_t)d1 * 256 + d0] = s;         // swt[ci*256+co] = tapsum(w[co,ci])
    }
}

// ---- Node 2: 256 blocks = (n, co-chunk of 64). Each thread: 64-ci partial dot;
//      4-way LDS combine. out[n,co] = acc/1225 + bias[co]. ----
__global__ __launch_bounds__(256) void k_gemm(const float* __restrict__ sx,
                                              const float* __restrict__ swt,
                                              const float* __restrict__ bias,
                                              float* __restrict__ out) {
    const int b     = blockIdx.x;   // 256
    const int n     = b >> 2;
    const int chunk = b & 3;
    const int tid   = threadIdx.x;
    const int q     = tid >> 6;     // ci quarter
    const int col   = tid & 63;
    const int co    = chunk * 64 + col;

    __shared__ float sxr[256];
    sxr[tid] = sx[n * 256 + tid];
    __syncthreads();

    const float* swp = swt + (size_t)(q * 64) * 256 + co;
    const float* sxp = sxr + q * 64;
    float acc = 0.f;
    #pragma unroll 8
    for (int i = 0; i < 64; ++i) acc += sxp[i] * swp[(size_t)i * 256];

    __shared__ float red[4][64];
    red[q][col] = acc;
    __syncthreads();
    if (tid < 64) {
        const float r = red[0][tid] + red[1][tid] + red[2][tid] + red[3][tid];
        out[n * 256 + chunk * 64 + tid] = r * (1.0f / 1225.0f) + bias[chunk * 64 + tid];
    }
}

extern "C" void kernel_launch(void* const* d_in, const int* in_sizes, int n_in,
                              void* d_out, int out_size, void* d_ws, size_t ws_size,
                              hipStream_t stream) {
    const float* x    = (const float*)d_in[0];  // [64,256,32,32]
    const float* w    = (const float*)d_in[1];  // [256,256,4,4]
    const float* bias = (const float*)d_in[2];  // [256]
    float* out = (float*)d_out;                 // [64,256,1,1] fp32

    float* sx  = (float*)d_ws;                  // 64*256 floats
    float* swt = sx + 64 * 256;                 // 256*256 floats

    k_reduce<<<XBLOCKS + 256, 256, 0, stream>>>(x, w, sx, swt);
    k_gemm<<<256, 256, 0, stream>>>(sx, swt, bias, out);
}

// Round 7
// 20.682 us; speedup vs baseline: 1.0191x; 1.0191x over previous
//
#include <hip/hip_runtime.h>

// out[n,co] = (1/1225) * sum_ci Sx[n,ci] * Sw[co,ci] + bias[co]   (exact; absmax 0.0 since R2)
//   Sx[n,ci]   = sum over 32x32 spatial of x[n,ci]
//   swt[ci,co] = tapsum(w[co,ci,:,:])   (stored transposed for coalesced gemm reads)
//
// R5 configuration — best measured (20.69 us). R6's deeper-ILP variant (16 loads
// in flight, 1024 blocks) regressed to 21.1: the reduce is BW-bound, not
// latency-bound. 8 rows/block x 2048 blocks is the sweet spot.

#define XBLOCKS 2048   // 16384 rows / 8 rows per block

// ---- Node 1: blocks [0,2048) reduce x (8 rows each, 8 loads in flight);
//      blocks [2048,2304) reduce w (one d0 row each, stored transposed). ----
__global__ __launch_bounds__(256) void k_reduce(const float* __restrict__ x,
                                                const float* __restrict__ w,
                                                float* __restrict__ sx,
                                                float* __restrict__ swt) {
    const int b   = blockIdx.x;
    const int tid = threadIdx.x;
    if (b < XBLOCKS) {
        const int row0 = b * 8;  // n*256+c base
        const float4* p = reinterpret_cast<const float4*>(x + (size_t)row0 * 1024);
        float s[8];
        #pragma unroll
        for (int r = 0; r < 8; ++r) {           // 8 independent float4 loads in flight
            const float4 v = p[r * 256 + tid];
            s[r] = v.x + v.y + v.z + v.w;
        }
        #pragma unroll
        for (int o = 32; o >= 1; o >>= 1) {
            #pragma unroll
            for (int r = 0; r < 8; ++r) s[r] += __shfl_xor(s[r], o, 64);
        }
        __shared__ float ws4[4][8];             // [wave][row]
        const int lane = tid & 63;
        const int wid  = tid >> 6;
        if (lane == 0) {
            #pragma unroll
            for (int r = 0; r < 8; ++r) ws4[wid][r] = s[r];
        }
        __syncthreads();
        if (tid < 8)
            sx[row0 + tid] = ws4[0][tid] + ws4[1][tid] + ws4[2][tid] + ws4[3][tid];
    } else {
        const int d0 = b - XBLOCKS;             // weight dim0 (= co)
        const int d1 = tid;                     // weight dim1 (= ci)
        const float4* p = reinterpret_cast<const float4*>(w + ((size_t)d0 * 256 + d1) * 16);
        float s = 0.f;
        #pragma unroll
        for (int k = 0; k < 4; ++k) {
            const float4 v = p[k];
            s += v.x + v.y + v.z + v.w;
        }
        swt[(size_t)d1 * 256 + d0] = s;         // swt[ci*256+co] = tapsum(w[co,ci])
    }
}

// ---- Node 2: 256 blocks = (n, co-chunk of 64). Each thread: 64-ci partial dot;
//      4-way LDS combine. out[n,co] = acc/1225 + bias[co]. ----
__global__ __launch_bounds__(256) void k_gemm(const float* __restrict__ sx,
                                              const float* __restrict__ swt,
                                              const float* __restrict__ bias,
                                              float* __restrict__ out) {
    const int b     = blockIdx.x;   // 256
    const int n     = b >> 2;
    const int chunk = b & 3;
    const int tid   = threadIdx.x;
    const int q     = tid >> 6;     // ci quarter
    const int col   = tid & 63;
    const int co    = chunk * 64 + col;

    __shared__ float sxr[256];
    sxr[tid] = sx[n * 256 + tid];
    __syncthreads();

    const float* swp = swt + (size_t)(q * 64) * 256 + co;
    const float* sxp = sxr + q * 64;
    float acc = 0.f;
    #pragma unroll 8
    for (int i = 0; i < 64; ++i) acc += sxp[i] * swp[(size_t)i * 256];

    __shared__ float red[4][64];
    red[q][col] = acc;
    __syncthreads();
    if (tid < 64) {
        const float r = red[0][tid] + red[1][tid] + red[2][tid] + red[3][tid];
        out[n * 256 + chunk * 64 + tid] = r * (1.0f / 1225.0f) + bias[chunk * 64 + tid];
    }
}

extern "C" void kernel_launch(void* const* d_in, const int* in_sizes, int n_in,
                              void* d_out, int out_size, void* d_ws, size_t ws_size,
                              hipStream_t stream) {
    const float* x    = (const float*)d_in[0];  // [64,256,32,32]
    const float* w    = (const float*)d_in[1];  // [256,256,4,4]
    const float* bias = (const float*)d_in[2];  // [256]
    float* out = (float*)d_out;                 // [64,256,1,1] fp32

    float* sx  = (float*)d_ws;                  // 64*256 floats
    float* swt = sx + 64 * 256;                 // 256*256 floats

    k_reduce<<<XBLOCKS + 256, 256, 0, stream>>>(x, w, sx, swt);
    k_gemm<<<256, 256, 0, stream>>>(sx, swt, bias, out);
}